// Round 14
// baseline (169.064 us; speedup 1.0000x reference)
//
#include <hip/hip_runtime.h>
#include <math.h>

static constexpr int Bn = 8, Ln = 1024, Dm = 512, Hn = 8, DhN = 64;

typedef short bf16x8 __attribute__((ext_vector_type(8)));
typedef float f32x4 __attribute__((ext_vector_type(4)));
typedef _Float16 f16x4 __attribute__((ext_vector_type(4)));
typedef _Float16 f16x8 __attribute__((ext_vector_type(8)));
typedef unsigned int u32x4 __attribute__((ext_vector_type(4)));
typedef unsigned short u16x8 __attribute__((ext_vector_type(8)));

// 0.125 * log2(e): folds the 1/sqrt(dh) scale AND the exp->exp2 conversion
#define QSCALE 0.1803368801111137f

static __device__ __forceinline__ unsigned short f2b(float f) {
  union { float f; unsigned int u; } x;
  x.f = f;
  unsigned int u = x.u;
  unsigned int r = (u + 0x7FFFu + ((u >> 16) & 1u)) >> 16;  // RNE
  return (unsigned short)r;
}
static __device__ __forceinline__ float b2f(unsigned short u) {
  union { unsigned int u; float f; } x;
  x.u = ((unsigned int)u) << 16;
  return x.f;
}

#define GLDS16(g, l)                                                        \
  __builtin_amdgcn_global_load_lds((const __attribute__((address_space(1))) void*)(g), \
                                   (__attribute__((address_space(3))) void*)(l), 16, 0, 0)

// ---------------- prep1: LN + PE + weight conversions + wkaug/uwvw (one dispatch) ----------------
// New vs R12: builds wkaug = [w_k | w_pos] (512x1024, for the fused K' GEMM) and
// wbias rows 0..7 = [w_k^T u_h | w_pos^T v_h] (the bias-as-GEMM-columns trick), rows 8..63 = 0,
// plus ubkb[h] = u_h . b_k_h.
__global__ __launch_bounds__(256) void prep1(const float* __restrict__ x,
                                             const float* __restrict__ gamma,
                                             const float* __restrict__ beta,
                                             const float* __restrict__ wq,
                                             const float* __restrict__ wp,
                                             const float* __restrict__ wo,
                                             const float* __restrict__ bq,
                                             const float* __restrict__ ub,
                                             const float* __restrict__ vb,
                                             unsigned short* __restrict__ xn,
                                             unsigned short* __restrict__ pe,
                                             unsigned short* __restrict__ wqb,
                                             unsigned short* __restrict__ wob,
                                             unsigned short* __restrict__ wkaug,
                                             unsigned short* __restrict__ wbias,
                                             float* __restrict__ ubkb) {
  int b = blockIdx.x;
  int t = threadIdx.x;
  if (b < 4096) {
    // LayerNorm, 2 rows/block, float4 loads
    int row = b * 2 + (t >> 7);
    int tl = t & 127;
    const float4 v = *(const float4*)(x + (size_t)row * Dm + tl * 4);
    float s = v.x + v.y + v.z + v.w;
    float sq = v.x * v.x + v.y * v.y + v.z * v.z + v.w * v.w;
#pragma unroll
    for (int off = 32; off > 0; off >>= 1) {
      s += __shfl_down(s, off);
      sq += __shfl_down(sq, off);
    }
    __shared__ float red[8];
    int wave = t >> 6, lane = t & 63;
    if (lane == 0) { red[wave * 2] = s; red[wave * 2 + 1] = sq; }
    __syncthreads();
    int half = t >> 7;
    float S = red[half * 4 + 0] + red[half * 4 + 2];
    float SQ = red[half * 4 + 1] + red[half * 4 + 3];
    float mu = S * (1.0f / Dm);
    float var = SQ * (1.0f / Dm) - mu * mu;
    float rstd = rsqrtf(var + 1e-5f);
    int c = tl * 4;
    const float4 g4 = *(const float4*)(gamma + c);
    const float4 b4 = *(const float4*)(beta + c);
    ushort4 o;
    o.x = f2b((v.x - mu) * rstd * g4.x + b4.x);
    o.y = f2b((v.y - mu) * rstd * g4.y + b4.y);
    o.z = f2b((v.z - mu) * rstd * g4.z + b4.z);
    o.w = f2b((v.w - mu) * rstd * g4.w + b4.w);
    *(ushort4*)(xn + (size_t)row * Dm + c) = o;
  } else if (b < 6144) {
    int idx = (b - 4096) * 256 + t;
    int l = idx >> 9, k = idx & 511;
    float freq = __expf(-0.0359778921f * (float)k);
    float angle = (float)(l - k) * freq;
    pe[idx] = f2b((k & 1) ? __sinf(angle) : __cosf(angle));
  } else if (b < 7168) {
    // wqkv (all 1536 rows; K'-rows also duplicated into wkaug below) + wout conversion
    int cb = b - 6144;  // 0..1023
    const float* src;
    unsigned short* dst;
    int off;
    if (cb < 768) { src = wq; dst = wqb; off = cb; }
    else { src = wo; dst = wob; off = cb - 768; }
    int i = off * 256 + t;
    float4 v = *(const float4*)(src + (size_t)i * 4);
    ushort4 o;
    o.x = f2b(v.x); o.y = f2b(v.y); o.z = f2b(v.z); o.w = f2b(v.w);
    *(ushort4*)(dst + (size_t)i * 4) = o;
  } else if (b < 7424) {
    // wkaug left half: w_qkv rows 512..1023 -> wkaug[r][0..511]
    int i = (b - 7168) * 256 + t;
    int e = i * 4, r = e >> 9, c = e & 511;
    float4 v = *(const float4*)(wq + (size_t)(512 + r) * 512 + c);
    ushort4 o;
    o.x = f2b(v.x); o.y = f2b(v.y); o.z = f2b(v.z); o.w = f2b(v.w);
    *(ushort4*)(wkaug + (size_t)r * 1024 + c) = o;
  } else if (b < 7680) {
    // wkaug right half: w_pos rows -> wkaug[r][512..1023]
    int i = (b - 7424) * 256 + t;
    int e = i * 4, r = e >> 9, c = e & 511;
    float4 v = *(const float4*)(wp + (size_t)r * 512 + c);
    ushort4 o;
    o.x = f2b(v.x); o.y = f2b(v.y); o.z = f2b(v.z); o.w = f2b(v.w);
    *(ushort4*)(wkaug + (size_t)r * 1024 + 512 + c) = o;
  } else if (b < 7688) {
    // uwvw: wbias row h = [w_k^T u_h (512) | w_pos^T v_h (512)], + ubk[h] = u_h . b_k_h
    int h = b - 7680;
    int k4 = t * 4;  // wave-uniform branch: t<128 <=> k4<512
    float a0 = 0.f, a1 = 0.f, a2 = 0.f, a3 = 0.f;
    for (int dh = 0; dh < 64; ++dh) {
      float s;
      const float* wr;
      if (k4 < 512) { s = ub[h * 64 + dh]; wr = wq + (size_t)(512 + h * 64 + dh) * 512 + k4; }
      else { s = vb[h * 64 + dh]; wr = wp + (size_t)(h * 64 + dh) * 512 + (k4 - 512); }
      float4 w4 = *(const float4*)wr;
      a0 += s * w4.x; a1 += s * w4.y; a2 += s * w4.z; a3 += s * w4.w;
    }
    ushort4 o;
    o.x = f2b(a0); o.y = f2b(a1); o.z = f2b(a2); o.w = f2b(a3);
    *(ushort4*)(wbias + h * 1024 + k4) = o;
    if (t < 64) {
      float pu = ub[h * 64 + t] * bq[512 + h * 64 + t];
#pragma unroll
      for (int off = 32; off > 0; off >>= 1) pu += __shfl_down(pu, off);
      if (t == 0) ubkb[h] = pu;
    }
  } else {
    // zero wbias rows 8..63
    int row = 8 + (b - 7688);
    ushort4 z = {0, 0, 0, 0};
    *(ushort4*)(wbias + row * 1024 + t * 4) = z;
  }
}

// ---------------- gemm3: fused QKV' GEMM -- Q | K'(=k+pos, K=1024) | V(transposed out) | bias cols ----------------
// bx 0..7: Q (K=512); 8..15: K' via A=[xn|pe], B=wkaug (K=1024); 16..23: V (K=512, epilogue
// writes vt directly via LDS transpose); 24: bias cols (K=1024, B=wbias, 8 real cols).
// This deletes the pos GEMM, the fold pass, the V row-layout buffer, and the prep2 dispatch.
// 64x64 tile BK=128, 32KB LDS, 5 blocks/CU. XCD remap bijective on 128x25=3200.
__global__ __launch_bounds__(256, 5) void gemm3(const unsigned short* __restrict__ xn,
                                                const unsigned short* __restrict__ pe,
                                                const unsigned short* __restrict__ wqb,
                                                const unsigned short* __restrict__ wkaug,
                                                const unsigned short* __restrict__ wbias,
                                                const float* __restrict__ bq,
                                                const float* __restrict__ ubkb,
                                                unsigned short* __restrict__ oq,
                                                unsigned short* __restrict__ ok,
                                                unsigned short* __restrict__ vtb,
                                                float* __restrict__ biasb) {
  int by = blockIdx.y, bx = blockIdx.x;
  {
    int lid = by * 25 + bx;
    int i = lid >> 3;
    by = (lid & 7) * 16 + i / 25;
    bx = i % 25;
  }
  int part, brow, KK, bstride;
  const unsigned short* Bw;
  if (bx < 8) { part = 0; Bw = wqb; brow = bx * 64; KK = 512; bstride = 512; }
  else if (bx < 16) { part = 1; Bw = wkaug; brow = (bx - 8) * 64; KK = 1024; bstride = 1024; }
  else if (bx < 24) { part = 2; Bw = wqb + (size_t)1024 * 512; brow = (bx - 16) * 64; KK = 512; bstride = 512; }
  else { part = 3; Bw = wbias; brow = 0; KK = 1024; bstride = 1024; }

  __shared__ alignas(16) unsigned short As[64 * 128];
  __shared__ alignas(16) unsigned short Bs[64 * 128];
  const int t = threadIdx.x;
  const int lane = t & 63, w = t >> 6;
  const int c = lane & 15, q8 = lane >> 4;
  const int wm = (w & 1) * 32, wn = (w >> 1) * 32;
  const int m0 = by * 64;
  const int b_ = m0 >> 10, l0 = m0 & 1023;

  f32x4 acc[2][2];
#pragma unroll
  for (int i = 0; i < 2; ++i)
#pragma unroll
    for (int j = 0; j < 2; ++j) acc[i][j] = (f32x4){0.f, 0.f, 0.f, 0.f};

  // staging: 256 threads x 16B = 16 rows/pass (16 granules); 4 passes per 64x128 array.
  const int srow = t >> 4;
  const int sgr = (t & 15) ^ srow;

  for (int k0 = 0; k0 < KK; k0 += 128) {
    __syncthreads();
#pragma unroll
    for (int p = 0; p < 4; ++p) {
      int r = p * 16 + srow;
      const unsigned short* asrc =
          (k0 < 512) ? xn + (size_t)(m0 + r) * 512 + k0 + sgr * 8
                     : pe + (size_t)(l0 + r) * 512 + (k0 - 512) + sgr * 8;
      GLDS16(asrc, As + (p * 256 + t) * 8);
      GLDS16(Bw + (size_t)(brow + r) * bstride + k0 + sgr * 8, Bs + (p * 256 + t) * 8);
    }
    __syncthreads();
#pragma unroll
    for (int kk = 0; kk < 4; ++kk) {
      bf16x8 a[2], b[2];
      const int q = kk * 4 + q8;
#pragma unroll
      for (int i = 0; i < 2; ++i) {
        int r = wm + i * 16 + c;
        a[i] = *(const bf16x8*)&As[(r * 16 + (q ^ (r & 15))) * 8];
      }
#pragma unroll
      for (int j = 0; j < 2; ++j) {
        int r = wn + j * 16 + c;
        b[j] = *(const bf16x8*)&Bs[(r * 16 + (q ^ (r & 15))) * 8];
      }
#pragma unroll
      for (int i = 0; i < 2; ++i)
#pragma unroll
        for (int j = 0; j < 2; ++j)
          acc[i][j] = __builtin_amdgcn_mfma_f32_16x16x32_bf16(a[i], b[j], acc[i][j], 0, 0, 0);
    }
  }

  if (part == 2) {
    // V: LDS transpose (reuse As as 64x68 tile), write vt fp16 (b,h,d,perm(l)) directly
    unsigned short* Ts = As;
    __syncthreads();  // all frag reads done before overwrite
#pragma unroll
    for (int i = 0; i < 2; ++i)
#pragma unroll
      for (int r = 0; r < 4; ++r) {
        int ar = wm + i * 16 + q8 * 4 + r;
#pragma unroll
        for (int j = 0; j < 2; ++j) {
          int ac = wn + j * 16 + c;
          float val = acc[i][j][r] + bq[1024 + brow + ac];
          union { _Float16 hv; unsigned short u; } cv;
          cv.hv = (_Float16)val;
          Ts[ar * 68 + ac] = cv.u;
        }
      }
    __syncthreads();
    int bh_ = b_ * 8 + (brow >> 6);
    int lt = l0 >> 6;
#pragma unroll
    for (int s = 0; s < 4; ++s) {
      int idx = t + s * 256;
      int d = idx >> 4, l4 = (idx & 15) << 2;
      ushort4 o4;
      o4.x = Ts[(l4 + 0) * 68 + d];
      o4.y = Ts[(l4 + 1) * 68 + d];
      o4.z = Ts[(l4 + 2) * 68 + d];
      o4.w = Ts[(l4 + 3) * 68 + d];
      int pb = ((l4 >> 5) & 1) * 32 + ((l4 >> 2) & 3) * 8 + ((l4 >> 4) & 1) * 4;
      *(ushort4*)(vtb + (size_t)bh_ * 65536 + d * 1024 + lt * 64 + pb) = o4;
    }
  } else if (part == 3) {
    // bias columns: col<8 valid; bias = (xn.uw + pe.vw + u.b_k) * QSCALE
#pragma unroll
    for (int i = 0; i < 2; ++i)
#pragma unroll
      for (int r = 0; r < 4; ++r) {
        int m = m0 + wm + i * 16 + q8 * 4 + r;
#pragma unroll
        for (int j = 0; j < 2; ++j) {
          int col = wn + j * 16 + c;
          if (col < 8) {
            float val = acc[i][j][r] + ubkb[col];
            biasb[(size_t)(b_ * 8 + col) * 1024 + (m & 1023)] = val * QSCALE;
          }
        }
      }
  } else {
    // Q (scaled) / K' scatter to (B,H,L,Dh) bf16
#pragma unroll
    for (int i = 0; i < 2; ++i)
#pragma unroll
      for (int r = 0; r < 4; ++r) {
        int m = m0 + wm + i * 16 + q8 * 4 + r;
        int l = m & 1023;
#pragma unroll
        for (int j = 0; j < 2; ++j) {
          int ln = brow + wn + j * 16 + c;  // 0..511 within part
          int h = ln >> 6, dh = ln & 63;
          float val = acc[i][j][r];
          size_t idx = ((size_t)(b_ * 8 + h) * 1024 + l) * 64 + dh;
          if (part == 0) {
            oq[idx] = f2b((val + bq[ln]) * QSCALE);
          } else {
            ok[idx] = f2b(val + bq[512 + ln]);
          }
        }
      }
  }
}

// ---------------- bf16 MFMA NT GEMM: 64x64 tile (R3-exact) -- out-projection ----------------
__global__ __launch_bounds__(256, 8) void gemm_mfma(const unsigned short* __restrict__ Ain,
                                                    const unsigned short* __restrict__ Bwin,
                                                    const float* __restrict__ biasin,
                                                    float* __restrict__ outfin,
                                                    int K) {
  int by = blockIdx.y, bx = blockIdx.x;
  {
    int NBX = gridDim.x;
    int lid = by * NBX + bx;
    int i = lid >> 3;
    by = (lid & 7) * 16 + i / NBX;
    bx = i % NBX;
  }
  const unsigned short* A = Ain;
  const unsigned short* Bw = Bwin;
  const float* bias = biasin;
  float* outf = outfin;
  __shared__ alignas(16) unsigned short As[64 * 64];
  __shared__ alignas(16) unsigned short Bs[64 * 64];
  const int t = threadIdx.x;
  const int lane = t & 63, w = t >> 6;
  const int c = lane & 15, q8 = lane >> 4;
  const int wm = (w & 1) * 32, wn = (w >> 1) * 32;
  const int m0 = by * 64, n0 = bx * 64;

  f32x4 acc[2][2];
#pragma unroll
  for (int i = 0; i < 2; ++i)
#pragma unroll
    for (int j = 0; j < 2; ++j) acc[i][j] = (f32x4){0.f, 0.f, 0.f, 0.f};

  const int srow = lane >> 3;
  const int sgr = (lane & 7) ^ srow;

  for (int k0 = 0; k0 < K; k0 += 64) {
    __syncthreads();
#pragma unroll
    for (int j = 0; j < 2; ++j) {
      int r = j * 32 + w * 8 + srow;
      GLDS16(A + (size_t)(m0 + r) * K + k0 + sgr * 8, As + (j * 256 + w * 64 + lane) * 8);
      GLDS16(Bw + (size_t)(n0 + r) * K + k0 + sgr * 8, Bs + (j * 256 + w * 64 + lane) * 8);
    }
    __syncthreads();
#pragma unroll
    for (int kk = 0; kk < 2; ++kk) {
      bf16x8 a[2], b[2];
      const int q = kk * 4 + q8;
#pragma unroll
      for (int i = 0; i < 2; ++i) {
        int r = wm + i * 16 + c;
        a[i] = *(const bf16x8*)&As[(r * 8 + (q ^ (r & 7))) * 8];
      }
#pragma unroll
      for (int j = 0; j < 2; ++j) {
        int r = wn + j * 16 + c;
        b[j] = *(const bf16x8*)&Bs[(r * 8 + (q ^ (r & 7))) * 8];
      }
#pragma unroll
      for (int i = 0; i < 2; ++i)
#pragma unroll
        for (int j = 0; j < 2; ++j)
          acc[i][j] = __builtin_amdgcn_mfma_f32_16x16x32_bf16(a[i], b[j], acc[i][j], 0, 0, 0);
    }
  }
#pragma unroll
  for (int i = 0; i < 2; ++i) {
#pragma unroll
    for (int r = 0; r < 4; ++r) {
      int m = m0 + wm + i * 16 + q8 * 4 + r;
#pragma unroll
      for (int j = 0; j < 2; ++j) {
        int n = n0 + wn + j * 16 + c;
        outf[(size_t)m * 512 + n] = acc[i][j][r] + bias[n];
      }
    }
  }
}

// ---------------- Flash attention v7 (empirical best ~32us): XCD-local K/V reuse ----------------
__global__ __launch_bounds__(256, 2) void flash_mfma(const unsigned short* __restrict__ qbf,
                                                     const unsigned short* __restrict__ kbf,
                                                     const unsigned short* __restrict__ vt,
                                                     const float* __restrict__ bias,
                                                     unsigned short* __restrict__ attn_out) {
  __shared__ alignas(16) unsigned short Ks[2][64 * 64];  // key-halves; rows=key, swizzled granules over d
  __shared__ alignas(16) unsigned short Vs[2][64 * 64];  // key-halves; rows=d, swizzled granules over perm(key)
  __shared__ alignas(16) float Bls[1024];
  const int t = threadIdx.x;
  const int lane = t & 63, w = t >> 6;              // w in [0,4)
  const int c = lane & 15, q8 = lane >> 4;
  const int cc7 = c & 7;
  // XCD-locality remap: lid&7 = XCD; bh = xcd*8 + mid, qt = top  (bijective on 512)
  const int lid = blockIdx.x + (blockIdx.y << 3);
  const int bh = ((lid & 7) << 3) + ((lid >> 3) & 7);
  const int qt = lid >> 6;
  const unsigned short* qg = qbf + (size_t)bh * 65536;
  const unsigned short* kg = kbf + (size_t)bh * 65536;
  const unsigned short* vg = vt + (size_t)bh * 65536;
  const float* bg = bias + (size_t)bh * 1024;

  // stage bias once (4 KB): 256 threads x 16 B
  GLDS16(bg + t * 4, Bls + t * 4);

  // Q for both query groups, register-resident
  bf16x8 bq[2][2];
#pragma unroll
  for (int g = 0; g < 2; ++g) {
    int qlg = qt * 128 + g * 64 + w * 16 + c;
    bq[g][0] = *(const bf16x8*)(qg + (size_t)qlg * 64 + q8 * 8);
    bq[g][1] = *(const bf16x8*)(qg + (size_t)qlg * 64 + 32 + q8 * 8);
  }

  float m_st[2] = {-INFINITY, -INFINITY};
  float l_st[2] = {0.0f, 0.0f};  // per-lane PARTIAL sums (reduced across q8 in epilogue)
  f32x4 o[2][4];
#pragma unroll
  for (int g = 0; g < 2; ++g)
#pragma unroll
    for (int i = 0; i < 4; ++i) o[g][i] = (f32x4){0.f, 0.f, 0.f, 0.f};

  // staging geometry: 4 waves x 64 lanes x 2 row-sets cover 64 rows x 8 granules per array half.
  const int srow = lane >> 3;
  const int sgr = (lane & 7) ^ srow;
  const int r0 = w * 16 + srow;  // rows r0, r0+8

  // prefetch it=0 into VGPRs
  u32x4 pk[2][2], pv[2][2];
#pragma unroll
  for (int h = 0; h < 2; ++h)
#pragma unroll
    for (int j = 0; j < 2; ++j) {
      int r = r0 + j * 8;
      pk[h][j] = *(const u32x4*)(kg + (size_t)(h * 64 + r) * 64 + sgr * 8);
      pv[h][j] = *(const u32x4*)(vg + (size_t)r * 1024 + h * 64 + sgr * 8);
    }

  for (int it = 0; it < 8; ++it) {
    __syncthreads();  // prior iteration's LDS reads done
#pragma unroll
    for (int h = 0; h < 2; ++h)
#pragma unroll
      for (int j = 0; j < 2; ++j) {
        int r = r0 + j * 8;
        *(u32x4*)&Ks[h][(r * 8 + (lane & 7)) * 8] = pk[h][j];
        *(u32x4*)&Vs[h][(r * 8 + (lane & 7)) * 8] = pv[h][j];
      }
    __syncthreads();
    // prefetch next iteration (latency overlaps compute below)
    if (it < 7) {
#pragma unroll
      for (int h = 0; h < 2; ++h)
#pragma unroll
        for (int j = 0; j < 2; ++j) {
          int r = r0 + j * 8;
          pk[h][j] = *(const u32x4*)(kg + (size_t)((it + 1) * 128 + h * 64 + r) * 64 + sgr * 8);
          pv[h][j] = *(const u32x4*)(vg + (size_t)r * 1024 + (it + 1) * 128 + h * 64 + sgr * 8);
        }
    }

    // S^T for both key-halves and both query groups; K-frag + bias reads shared across groups
    f32x4 sc[2][2][4];
#pragma unroll
    for (int h = 0; h < 2; ++h) {
#pragma unroll
      for (int nt = 0; nt < 4; ++nt) {
        f32x4 ci = *(const f32x4*)&Bls[it * 128 + h * 64 + nt * 16 + q8 * 4];
        const int row = nt * 16 + c;
        bf16x8 ak0 = *(const bf16x8*)&Ks[h][(row * 8 + (q8 ^ cc7)) * 8];
        bf16x8 ak1 = *(const bf16x8*)&Ks[h][(row * 8 + ((q8 + 4) ^ cc7)) * 8];
#pragma unroll
        for (int g = 0; g < 2; ++g) {
          f32x4 z = __builtin_amdgcn_mfma_f32_16x16x32_bf16(ak0, bq[g][0], ci, 0, 0, 0);
          sc[g][h][nt] = __builtin_amdgcn_mfma_f32_16x16x32_bf16(ak1, bq[g][1], z, 0, 0, 0);
        }
      }
    }
    // online softmax: local maxima first, then INTERLEAVED cross-lane reductions
    float mx[2];
#pragma unroll
    for (int g = 0; g < 2; ++g) {
      float m = sc[g][0][0][0];
#pragma unroll
      for (int h = 0; h < 2; ++h)
#pragma unroll
        for (int nt = 0; nt < 4; ++nt)
#pragma unroll
          for (int r = 0; r < 4; ++r) m = fmaxf(m, sc[g][h][nt][r]);
      mx[g] = m;
    }
    {
      float s0 = __shfl_xor(mx[0], 16);
      float s1 = __shfl_xor(mx[1], 16);
      mx[0] = fmaxf(mx[0], s0);
      mx[1] = fmaxf(mx[1], s1);
      s0 = __shfl_xor(mx[0], 32);
      s1 = __shfl_xor(mx[1], 32);
      mx[0] = fmaxf(mx[0], s0);
      mx[1] = fmaxf(mx[1], s1);
    }
    // P packed for x32 PV: pf8[g][h][kk] holds keys kk*32 + q8*8 + {tile 2kk: r | tile 2kk+1: 4+r}
    f16x8 pf8[2][2][2];
#pragma unroll
    for (int g = 0; g < 2; ++g) {
      float mn = fmaxf(m_st[g], mx[g]);
      float al = __builtin_amdgcn_exp2f(m_st[g] - mn);
      float su = 0.0f;
#pragma unroll
      for (int h = 0; h < 2; ++h)
#pragma unroll
        for (int nt = 0; nt < 4; ++nt)
#pragma unroll
          for (int r = 0; r < 4; ++r) {
            float p = __builtin_amdgcn_exp2f(sc[g][h][nt][r] - mn);
            su += p;
            pf8[g][h][nt >> 1][((nt & 1) << 2) | r] = (_Float16)p;
          }
      l_st[g] = l_st[g] * al + su;  // per-lane partial (al is query-uniform)
      m_st[g] = mn;
#pragma unroll
      for (int i = 0; i < 4; ++i) o[g][i] *= al;
    }
    // O^T += V^T . P^T  (fp16 x32; V-frag reads shared across groups)
#pragma unroll
    for (int i = 0; i < 4; ++i) {
      const int row = i * 16 + c;
#pragma unroll
      for (int h = 0; h < 2; ++h) {
        f16x8 va = *(const f16x8*)&Vs[h][(row * 8 + (q8 ^ cc7)) * 8];        // granule kk=0
        f16x8 vb = *(const f16x8*)&Vs[h][(row * 8 + ((4 + q8) ^ cc7)) * 8];  // granule kk=1
#pragma unroll
        for (int g = 0; g < 2; ++g) {
          o[g][i] = __builtin_amdgcn_mfma_f32_16x16x32_f16(va, pf8[g][h][0], o[g][i], 0, 0, 0);
          o[g][i] = __builtin_amdgcn_mfma_f32_16x16x32_f16(vb, pf8[g][h][1], o[g][i], 0, 0, 0);
        }
      }
    }
  }
  // epilogue: reduce the deferred l partials across q8 lanes, then write O^T
  float lt0 = l_st[0], lt1 = l_st[1];
  {
    float s0 = __shfl_xor(lt0, 16);
    float s1 = __shfl_xor(lt1, 16);
    lt0 += s0; lt1 += s1;
    s0 = __shfl_xor(lt0, 32);
    s1 = __shfl_xor(lt1, 32);
    lt0 += s0; lt1 += s1;
  }
  const int bidx = bh >> 3, h = bh & 7;
#pragma unroll
  for (int g = 0; g < 2; ++g) {
    int qlg = qt * 128 + g * 64 + w * 16 + c;
    float inv = 1.0f / (g == 0 ? lt0 : lt1);
    size_t base = (size_t)(bidx * 1024 + qlg) * 512 + h * 64;
#pragma unroll
    for (int i = 0; i < 4; ++i) {
      ushort4 ov4;
      ov4.x = f2b(o[g][i][0] * inv);
      ov4.y = f2b(o[g][i][1] * inv);
      ov4.z = f2b(o[g][i][2] * inv);
      ov4.w = f2b(o[g][i][3] * inv);
      *(ushort4*)(attn_out + base + i * 16 + q8 * 4) = ov4;
    }
  }
}

extern "C" void kernel_launch(void* const* d_in, const int* in_sizes, int n_in,
                              void* d_out, int out_size, void* d_ws, size_t ws_size,
                              hipStream_t stream) {
  const float* x      = (const float*)d_in[0];
  const float* gamma  = (const float*)d_in[1];
  const float* beta   = (const float*)d_in[2];
  const float* w_qkv  = (const float*)d_in[3];
  const float* b_qkv  = (const float*)d_in[4];
  const float* w_pos  = (const float*)d_in[5];
  const float* w_out  = (const float*)d_in[6];
  const float* b_out  = (const float*)d_in[7];
  const float* u_bias = (const float*)d_in[8];
  const float* v_bias = (const float*)d_in[9];
  float* out = (float*)d_out;

  unsigned short* wsu = (unsigned short*)d_ws;
  unsigned short* xnb   = wsu;                    // 4M ushort
  unsigned short* peb   = wsu + 4194304;          // 512K
  unsigned short* wqkvb = wsu + 4718592;          // 768K
  unsigned short* woutb = wsu + 5505024;          // 256K
  unsigned short* wkaug = wsu + 5767168;          // 512K (512x1024)
  unsigned short* wbias = wsu + 6291456;          // 64K (64x1024)
  unsigned short* qbf   = wsu + 6356992;          // 4M (bf16, pre-scaled)
  unsigned short* kbf   = wsu + 10551296;         // 4M (K' bf16, fused)
  unsigned short* vtb   = wsu + 14745600;         // 4M (fp16, permuted-transposed)
  unsigned short* attnb = wsu + 18939904;         // 4M (bf16)
  float* biasb = (float*)(wsu + 23134208);        // 64K floats (pre-scaled)
  float* ubkb  = (float*)(wsu + 23265280);        // 8 floats

  prep1<<<7744, 256, 0, stream>>>(x, gamma, beta, w_qkv, w_pos, w_out, b_qkv, u_bias, v_bias,
                                  xnb, peb, wqkvb, woutb, wkaug, wbias, ubkb);
  gemm3<<<dim3(25, 128), 256, 0, stream>>>(xnb, peb, wqkvb, wkaug, wbias, b_qkv, ubkb,
                                           qbf, kbf, vtb, biasb);
  flash_mfma<<<dim3(8, 64), 256, 0, stream>>>(qbf, kbf, vtb, biasb, attnb);
  gemm_mfma<<<dim3(8, 128), 256, 0, stream>>>(attnb, woutb, b_out, out, 512);
}

// Round 15
// 159.683 us; speedup vs baseline: 1.0588x; 1.0588x over previous
//
#include <hip/hip_runtime.h>
#include <math.h>

static constexpr int Bn = 8, Ln = 1024, Dm = 512, Hn = 8, DhN = 64;

typedef short bf16x8 __attribute__((ext_vector_type(8)));
typedef float f32x4 __attribute__((ext_vector_type(4)));
typedef _Float16 f16x4 __attribute__((ext_vector_type(4)));
typedef _Float16 f16x8 __attribute__((ext_vector_type(8)));
typedef unsigned int u32x4 __attribute__((ext_vector_type(4)));
typedef unsigned short u16x8 __attribute__((ext_vector_type(8)));

// 0.125 * log2(e): folds the 1/sqrt(dh) scale AND the exp->exp2 conversion
#define QSCALE 0.1803368801111137f

static __device__ __forceinline__ unsigned short f2b(float f) {
  union { float f; unsigned int u; } x;
  x.f = f;
  unsigned int u = x.u;
  unsigned int r = (u + 0x7FFFu + ((u >> 16) & 1u)) >> 16;  // RNE
  return (unsigned short)r;
}
static __device__ __forceinline__ float b2f(unsigned short u) {
  union { unsigned int u; float f; } x;
  x.u = ((unsigned int)u) << 16;
  return x.f;
}

#define GLDS16(g, l)                                                        \
  __builtin_amdgcn_global_load_lds((const __attribute__((address_space(1))) void*)(g), \
                                   (__attribute__((address_space(3))) void*)(l), 16, 0, 0)

// ---------------- prep1: LayerNorm + PE + weight conversions (one dispatch) ----------------
__global__ __launch_bounds__(256) void prep1(const float* __restrict__ x,
                                             const float* __restrict__ gamma,
                                             const float* __restrict__ beta,
                                             unsigned short* __restrict__ xn,
                                             unsigned short* __restrict__ pe,
                                             const float* __restrict__ wq, unsigned short* __restrict__ wqb,
                                             const float* __restrict__ wp, unsigned short* __restrict__ wpb,
                                             const float* __restrict__ wo, unsigned short* __restrict__ wob) {
  int b = blockIdx.x;
  int t = threadIdx.x;
  if (b < 8192) {
    // LayerNorm row b
    const float2 v = *(const float2*)(x + (size_t)b * Dm + t * 2);
    float s = v.x + v.y;
    float sq = v.x * v.x + v.y * v.y;
#pragma unroll
    for (int off = 32; off > 0; off >>= 1) {
      s += __shfl_down(s, off);
      sq += __shfl_down(sq, off);
    }
    __shared__ float red[8];
    int wave = t >> 6, lane = t & 63;
    if (lane == 0) { red[wave * 2] = s; red[wave * 2 + 1] = sq; }
    __syncthreads();
    float S = red[0] + red[2] + red[4] + red[6];
    float SQ = red[1] + red[3] + red[5] + red[7];
    float mu = S * (1.0f / Dm);
    float var = SQ * (1.0f / Dm) - mu * mu;
    float rstd = rsqrtf(var + 1e-5f);
    int c = t * 2;
    ushort2 o;
    o.x = f2b((v.x - mu) * rstd * gamma[c] + beta[c]);
    o.y = f2b((v.y - mu) * rstd * gamma[c + 1] + beta[c + 1]);
    *(ushort2*)(xn + (size_t)b * Dm + c) = o;
  } else if (b < 10240) {
    int idx = (b - 8192) * 256 + t;
    int l = idx >> 9, k = idx & 511;
    // HW-trig path: abs err ~6e-5, far below the bf16 quantization (0.004) applied to pe.
    float freq = __expf(-0.0359778921f * (float)k);
    float angle = (float)(l - k) * freq;
    pe[idx] = f2b((k & 1) ? __sinf(angle) : __cosf(angle));
  } else {
    int cb = b - 10240;  // 0..1279
    const float* src;
    unsigned short* dst;
    int off;
    if (cb < 768) { src = wq; dst = wqb; off = cb; }
    else if (cb < 1024) { src = wp; dst = wpb; off = cb - 768; }
    else { src = wo; dst = wob; off = cb - 1024; }
    int i = off * 256 + t;
    float4 v = *(const float4*)(src + (size_t)i * 4);
    ushort4 o;
    o.x = f2b(v.x); o.y = f2b(v.y); o.z = f2b(v.z); o.w = f2b(v.w);
    *(ushort4*)(dst + (size_t)i * 4) = o;
  }
}

// ---------------- gemm2: 128x64 asymmetric tile for the QKV (+pos) GEMM (R10/R12, best) ----------------
// mode 1 writes pos as BF16 (halves the fold pass's pos read traffic; pos is bf16-rounded
// when folded into K' anyway, and the bias's bf16-pos quantization is within tolerance).
__global__ __launch_bounds__(256, 6) void gemm2(const unsigned short* __restrict__ Ain,
                                                const unsigned short* __restrict__ Bwin,
                                                const float* __restrict__ biasin,
                                                unsigned short* __restrict__ oq,
                                                unsigned short* __restrict__ ok,
                                                unsigned short* __restrict__ ov,
                                                const unsigned short* __restrict__ A2,
                                                const unsigned short* __restrict__ B2,
                                                unsigned short* __restrict__ outp) {
  int by = blockIdx.y, bx = blockIdx.x;
  int mode = 0;
  const unsigned short* A = Ain;
  const unsigned short* Bw = Bwin;
  const float* bias = biasin;
  if (by < 64) {
    // XCD-locality remap, bijective on 64x24=1536
    int lid = by * 24 + bx;
    int i = lid >> 3;
    by = (lid & 7) * 8 + i / 24;
    bx = i % 24;
  } else {
    if (bx >= 8) return;
    A = A2; Bw = B2; bias = nullptr; mode = 1; by -= 64;
  }
  const int K = 512;
  __shared__ alignas(16) unsigned short As[128 * 64];
  __shared__ alignas(16) unsigned short Bs[64 * 64];
  const int t = threadIdx.x;
  const int lane = t & 63, w = t >> 6;
  const int c = lane & 15, q8 = lane >> 4;
  const int wm = (w & 1) * 64, wn = (w >> 1) * 32;
  const int m0 = by * 128, n0 = bx * 64;

  f32x4 acc[4][2];
#pragma unroll
  for (int i = 0; i < 4; ++i)
#pragma unroll
    for (int j = 0; j < 2; ++j) acc[i][j] = (f32x4){0.f, 0.f, 0.f, 0.f};

  const int srow = lane >> 3;
  const int sgr = (lane & 7) ^ srow;

  for (int k0 = 0; k0 < K; k0 += 64) {
    __syncthreads();
#pragma unroll
    for (int s = 0; s < 4; ++s) {
      int r = s * 32 + w * 8 + srow;
      GLDS16(A + (size_t)(m0 + r) * K + k0 + sgr * 8, As + (s * 256 + w * 64 + lane) * 8);
    }
#pragma unroll
    for (int s = 0; s < 2; ++s) {
      int r = s * 32 + w * 8 + srow;
      GLDS16(Bw + (size_t)(n0 + r) * K + k0 + sgr * 8, Bs + (s * 256 + w * 64 + lane) * 8);
    }
    __syncthreads();
#pragma unroll
    for (int kk = 0; kk < 2; ++kk) {
      bf16x8 a[4], b[2];
      const int q = kk * 4 + q8;
#pragma unroll
      for (int i = 0; i < 4; ++i) {
        int r = wm + i * 16 + c;
        a[i] = *(const bf16x8*)&As[(r * 8 + (q ^ (r & 7))) * 8];
      }
#pragma unroll
      for (int j = 0; j < 2; ++j) {
        int r = wn + j * 16 + c;
        b[j] = *(const bf16x8*)&Bs[(r * 8 + (q ^ (r & 7))) * 8];
      }
#pragma unroll
      for (int i = 0; i < 4; ++i)
#pragma unroll
        for (int j = 0; j < 2; ++j)
          acc[i][j] = __builtin_amdgcn_mfma_f32_16x16x32_bf16(a[i], b[j], acc[i][j], 0, 0, 0);
    }
  }
#pragma unroll
  for (int i = 0; i < 4; ++i) {
#pragma unroll
    for (int r = 0; r < 4; ++r) {
      int m = m0 + wm + i * 16 + q8 * 4 + r;
#pragma unroll
      for (int j = 0; j < 2; ++j) {
        int n = n0 + wn + j * 16 + c;
        float val = acc[i][j][r] + (bias ? bias[n] : 0.0f);
        if (mode == 0) {
          int part = n >> 9, h = (n >> 6) & 7, dh = n & 63;
          int bb = m >> 10, l = m & 1023;
          size_t idx = (size_t)((bb * 8 + h) * 1024 + l) * 64 + dh;
          if (part == 0) {
            oq[idx] = f2b(val * QSCALE);
          } else if (part == 1) {
            ok[idx] = f2b(val);
          } else {
            union { _Float16 h; unsigned short u; } cv;
            cv.h = (_Float16)val;
            ov[idx] = cv.u;
          }
        } else {
          int h = n >> 6, dh = n & 63;
          outp[(size_t)(h * 1024 + m) * 64 + dh] = f2b(val);
        }
      }
    }
  }
}

// ---------------- bf16 MFMA NT GEMM: 64x64 tile (R3-exact) -- out-projection ----------------
__global__ __launch_bounds__(256, 8) void gemm_mfma(const unsigned short* __restrict__ Ain,
                                                    const unsigned short* __restrict__ Bwin,
                                                    const float* __restrict__ biasin,
                                                    float* __restrict__ outfin,
                                                    int K) {
  int by = blockIdx.y, bx = blockIdx.x;
  {
    int NBX = gridDim.x;
    int lid = by * NBX + bx;
    int i = lid >> 3;
    by = (lid & 7) * 16 + i / NBX;
    bx = i % NBX;
  }
  const unsigned short* A = Ain;
  const unsigned short* Bw = Bwin;
  const float* bias = biasin;
  float* outf = outfin;
  __shared__ alignas(16) unsigned short As[64 * 64];
  __shared__ alignas(16) unsigned short Bs[64 * 64];
  const int t = threadIdx.x;
  const int lane = t & 63, w = t >> 6;
  const int c = lane & 15, q8 = lane >> 4;
  const int wm = (w & 1) * 32, wn = (w >> 1) * 32;
  const int m0 = by * 64, n0 = bx * 64;

  f32x4 acc[2][2];
#pragma unroll
  for (int i = 0; i < 2; ++i)
#pragma unroll
    for (int j = 0; j < 2; ++j) acc[i][j] = (f32x4){0.f, 0.f, 0.f, 0.f};

  const int srow = lane >> 3;
  const int sgr = (lane & 7) ^ srow;

  for (int k0 = 0; k0 < K; k0 += 64) {
    __syncthreads();
#pragma unroll
    for (int j = 0; j < 2; ++j) {
      int r = j * 32 + w * 8 + srow;
      GLDS16(A + (size_t)(m0 + r) * K + k0 + sgr * 8, As + (j * 256 + w * 64 + lane) * 8);
      GLDS16(Bw + (size_t)(n0 + r) * K + k0 + sgr * 8, Bs + (j * 256 + w * 64 + lane) * 8);
    }
    __syncthreads();
#pragma unroll
    for (int kk = 0; kk < 2; ++kk) {
      bf16x8 a[2], b[2];
      const int q = kk * 4 + q8;
#pragma unroll
      for (int i = 0; i < 2; ++i) {
        int r = wm + i * 16 + c;
        a[i] = *(const bf16x8*)&As[(r * 8 + (q ^ (r & 7))) * 8];
      }
#pragma unroll
      for (int j = 0; j < 2; ++j) {
        int r = wn + j * 16 + c;
        b[j] = *(const bf16x8*)&Bs[(r * 8 + (q ^ (r & 7))) * 8];
      }
#pragma unroll
      for (int i = 0; i < 2; ++i)
#pragma unroll
        for (int j = 0; j < 2; ++j)
          acc[i][j] = __builtin_amdgcn_mfma_f32_16x16x32_bf16(a[i], b[j], acc[i][j], 0, 0, 0);
    }
  }
#pragma unroll
  for (int i = 0; i < 2; ++i) {
#pragma unroll
    for (int r = 0; r < 4; ++r) {
      int m = m0 + wm + i * 16 + q8 * 4 + r;
#pragma unroll
      for (int j = 0; j < 2; ++j) {
        int n = n0 + wn + j * 16 + c;
        outf[(size_t)m * 512 + n] = acc[i][j][r] + bias[n];
      }
    }
  }
}

// ---------------- prep2: VECTORIZED fold (K'=k+pos, bias) + V transpose (one dispatch) ----------------
// Fold: short8 16B/lane (each thread folds 8 elements of one row; 32 rows/block, 2048 blocks).
// pos is bf16 (half the read traffic). Per-row bias via 3 shfl_xor over the 8 slot-lanes.
__global__ __launch_bounds__(256) void prep2(unsigned short* __restrict__ kbuf,
                                             const unsigned short* __restrict__ posbf,
                                             const float* __restrict__ ub,
                                             const float* __restrict__ vbb,
                                             float* __restrict__ biasout,
                                             const unsigned short* __restrict__ v,
                                             unsigned short* __restrict__ vt) {
  int b = blockIdx.x;
  int t = threadIdx.x;
  if (b < 2048) {
    int g = b * 32 + (t >> 3);  // row in [0, B*H*L)
    int s = t & 7;              // 8B-granule slot within the 64-elem row
    int h = (g >> 10) & 7;
    int m = g & 1023;
    u16x8 kv8 = *(const u16x8*)(kbuf + (size_t)g * 64 + s * 8);
    u16x8 pv8 = *(const u16x8*)(posbf + (size_t)(h * 1024 + m) * 64 + s * 8);
    f32x4 u0 = *(const f32x4*)(ub + h * 64 + s * 8);
    f32x4 u1 = *(const f32x4*)(ub + h * 64 + s * 8 + 4);
    f32x4 v0 = *(const f32x4*)(vbb + h * 64 + s * 8);
    f32x4 v1 = *(const f32x4*)(vbb + h * 64 + s * 8 + 4);
    float part = 0.0f;
    u16x8 o8;
#pragma unroll
    for (int e = 0; e < 8; ++e) {
      float kf = b2f(kv8[e]);
      float pf = b2f(pv8[e]);
      float ue = (e < 4) ? u0[e] : u1[e - 4];
      float ve = (e < 4) ? v0[e] : v1[e - 4];
      part += ue * kf + ve * pf;
      o8[e] = f2b(kf + pf);
    }
    *(u16x8*)(kbuf + (size_t)g * 64 + s * 8) = o8;
    part += __shfl_xor(part, 1);
    part += __shfl_xor(part, 2);
    part += __shfl_xor(part, 4);
    if (s == 0) biasout[g] = part * QSCALE;
  } else {
    // V fp16 (b,h,l,d) -> V2 fp16 (b,h,d,perm(l))
    // perm: dst = ((l>>5)&1)*32 + ((l>>2)&3)*8 + ((l>>4)&1)*4 + (l&3)
    __shared__ unsigned short Ts[64 * 68];
    int bb = b - 2048;
    int bh = bb >> 4, lt = bb & 15;
    const unsigned short* vg = v + (size_t)bh * 65536 + lt * 4096;
#pragma unroll
    for (int s = 0; s < 4; ++s) {
      int idx = t + s * 256;
      int r = idx >> 4, c4 = (idx & 15) << 2;
      *(ushort4*)&Ts[r * 68 + c4] = *(const ushort4*)(vg + r * 64 + c4);
    }
    __syncthreads();
#pragma unroll
    for (int s = 0; s < 4; ++s) {
      int idx = t + s * 256;
      int d = idx >> 4, l4 = (idx & 15) << 2;
      ushort4 o;
      o.x = Ts[(l4 + 0) * 68 + d];
      o.y = Ts[(l4 + 1) * 68 + d];
      o.z = Ts[(l4 + 2) * 68 + d];
      o.w = Ts[(l4 + 3) * 68 + d];
      int pb = ((l4 >> 5) & 1) * 32 + ((l4 >> 2) & 3) * 8 + ((l4 >> 4) & 1) * 4;  // l4&3 == 0
      *(ushort4*)(vt + (size_t)bh * 65536 + d * 1024 + lt * 64 + pb) = o;
    }
  }
}

// ---------------- Flash attention v7 (empirical best ~32us): XCD-local K/V reuse ----------------
// S^T = K'.Q^T (bf16 x32), O^T = V^T.P^T (fp16 x32), P stays in registers.
// grid (8, 64), 256 threads; wave w owns queries {w*16+c, 64+w*16+c}.
// Bijective XCD swizzle: all 8 qt-blocks sharing one bh's K/V (256 KB) land on ONE XCD;
// per-XCD set = 8 bh x 256 KB = 2 MB < 4 MB L2 (R7 verified: FETCH 72->18MB).
// Ledger: v8 (2x TLP+setprio) ~0/-, v9 (dbuf 1-barrier) -11us, v10 (zero-LDS) -27us,
// v11 (fused fold) -12us -- the 2-barrier reg-prefetch LDS structure is the measured optimum.
__global__ __launch_bounds__(256, 2) void flash_mfma(const unsigned short* __restrict__ qbf,
                                                     const unsigned short* __restrict__ kbf,
                                                     const unsigned short* __restrict__ vt,
                                                     const float* __restrict__ bias,
                                                     unsigned short* __restrict__ attn_out) {
  __shared__ alignas(16) unsigned short Ks[2][64 * 64];  // key-halves; rows=key, swizzled granules over d
  __shared__ alignas(16) unsigned short Vs[2][64 * 64];  // key-halves; rows=d, swizzled granules over perm(key)
  __shared__ alignas(16) float Bls[1024];
  const int t = threadIdx.x;
  const int lane = t & 63, w = t >> 6;              // w in [0,4)
  const int c = lane & 15, q8 = lane >> 4;
  const int cc7 = c & 7;
  // XCD-locality remap: lid&7 = XCD; bh = xcd*8 + mid, qt = top  (bijective on 512)
  const int lid = blockIdx.x + (blockIdx.y << 3);
  const int bh = ((lid & 7) << 3) + ((lid >> 3) & 7);
  const int qt = lid >> 6;
  const unsigned short* qg = qbf + (size_t)bh * 65536;
  const unsigned short* kg = kbf + (size_t)bh * 65536;
  const unsigned short* vg = vt + (size_t)bh * 65536;
  const float* bg = bias + (size_t)bh * 1024;

  // stage bias once (4 KB): 256 threads x 16 B
  GLDS16(bg + t * 4, Bls + t * 4);

  // Q for both query groups, register-resident
  bf16x8 bq[2][2];
#pragma unroll
  for (int g = 0; g < 2; ++g) {
    int qlg = qt * 128 + g * 64 + w * 16 + c;
    bq[g][0] = *(const bf16x8*)(qg + (size_t)qlg * 64 + q8 * 8);
    bq[g][1] = *(const bf16x8*)(qg + (size_t)qlg * 64 + 32 + q8 * 8);
  }

  float m_st[2] = {-INFINITY, -INFINITY};
  float l_st[2] = {0.0f, 0.0f};  // per-lane PARTIAL sums (reduced across q8 in epilogue)
  f32x4 o[2][4];
#pragma unroll
  for (int g = 0; g < 2; ++g)
#pragma unroll
    for (int i = 0; i < 4; ++i) o[g][i] = (f32x4){0.f, 0.f, 0.f, 0.f};

  // staging geometry: 4 waves x 64 lanes x 2 row-sets cover 64 rows x 8 granules per array half.
  const int srow = lane >> 3;
  const int sgr = (lane & 7) ^ srow;
  const int r0 = w * 16 + srow;  // rows r0, r0+8

  // prefetch it=0 into VGPRs
  u32x4 pk[2][2], pv[2][2];
#pragma unroll
  for (int h = 0; h < 2; ++h)
#pragma unroll
    for (int j = 0; j < 2; ++j) {
      int r = r0 + j * 8;
      pk[h][j] = *(const u32x4*)(kg + (size_t)(h * 64 + r) * 64 + sgr * 8);
      pv[h][j] = *(const u32x4*)(vg + (size_t)r * 1024 + h * 64 + sgr * 8);
    }

  for (int it = 0; it < 8; ++it) {
    __syncthreads();  // prior iteration's LDS reads done
#pragma unroll
    for (int h = 0; h < 2; ++h)
#pragma unroll
      for (int j = 0; j < 2; ++j) {
        int r = r0 + j * 8;
        *(u32x4*)&Ks[h][(r * 8 + (lane & 7)) * 8] = pk[h][j];
        *(u32x4*)&Vs[h][(r * 8 + (lane & 7)) * 8] = pv[h][j];
      }
    __syncthreads();
    // prefetch next iteration (latency overlaps compute below)
    if (it < 7) {
#pragma unroll
      for (int h = 0; h < 2; ++h)
#pragma unroll
        for (int j = 0; j < 2; ++j) {
          int r = r0 + j * 8;
          pk[h][j] = *(const u32x4*)(kg + (size_t)((it + 1) * 128 + h * 64 + r) * 64 + sgr * 8);
          pv[h][j] = *(const u32x4*)(vg + (size_t)r * 1024 + (it + 1) * 128 + h * 64 + sgr * 8);
        }
    }

    // S^T for both key-halves and both query groups; K-frag + bias reads shared across groups
    f32x4 sc[2][2][4];
#pragma unroll
    for (int h = 0; h < 2; ++h) {
#pragma unroll
      for (int nt = 0; nt < 4; ++nt) {
        f32x4 ci = *(const f32x4*)&Bls[it * 128 + h * 64 + nt * 16 + q8 * 4];
        const int row = nt * 16 + c;
        bf16x8 ak0 = *(const bf16x8*)&Ks[h][(row * 8 + (q8 ^ cc7)) * 8];
        bf16x8 ak1 = *(const bf16x8*)&Ks[h][(row * 8 + ((q8 + 4) ^ cc7)) * 8];
#pragma unroll
        for (int g = 0; g < 2; ++g) {
          f32x4 z = __builtin_amdgcn_mfma_f32_16x16x32_bf16(ak0, bq[g][0], ci, 0, 0, 0);
          sc[g][h][nt] = __builtin_amdgcn_mfma_f32_16x16x32_bf16(ak1, bq[g][1], z, 0, 0, 0);
        }
      }
    }
    // online softmax: local maxima first, then INTERLEAVED cross-lane reductions
    float mx[2];
#pragma unroll
    for (int g = 0; g < 2; ++g) {
      float m = sc[g][0][0][0];
#pragma unroll
      for (int h = 0; h < 2; ++h)
#pragma unroll
        for (int nt = 0; nt < 4; ++nt)
#pragma unroll
          for (int r = 0; r < 4; ++r) m = fmaxf(m, sc[g][h][nt][r]);
      mx[g] = m;
    }
    {
      float s0 = __shfl_xor(mx[0], 16);
      float s1 = __shfl_xor(mx[1], 16);
      mx[0] = fmaxf(mx[0], s0);
      mx[1] = fmaxf(mx[1], s1);
      s0 = __shfl_xor(mx[0], 32);
      s1 = __shfl_xor(mx[1], 32);
      mx[0] = fmaxf(mx[0], s0);
      mx[1] = fmaxf(mx[1], s1);
    }
    // P packed for x32 PV: pf8[g][h][kk] holds keys kk*32 + q8*8 + {tile 2kk: r | tile 2kk+1: 4+r}
    f16x8 pf8[2][2][2];
#pragma unroll
    for (int g = 0; g < 2; ++g) {
      float mn = fmaxf(m_st[g], mx[g]);
      float al = __builtin_amdgcn_exp2f(m_st[g] - mn);
      float su = 0.0f;
#pragma unroll
      for (int h = 0; h < 2; ++h)
#pragma unroll
        for (int nt = 0; nt < 4; ++nt)
#pragma unroll
          for (int r = 0; r < 4; ++r) {
            float p = __builtin_amdgcn_exp2f(sc[g][h][nt][r] - mn);
            su += p;
            pf8[g][h][nt >> 1][((nt & 1) << 2) | r] = (_Float16)p;
          }
      l_st[g] = l_st[g] * al + su;  // per-lane partial (al is query-uniform)
      m_st[g] = mn;
#pragma unroll
      for (int i = 0; i < 4; ++i) o[g][i] *= al;
    }
    // O^T += V^T . P^T  (fp16 x32; V-frag reads shared across groups)
#pragma unroll
    for (int i = 0; i < 4; ++i) {
      const int row = i * 16 + c;
#pragma unroll
      for (int h = 0; h < 2; ++h) {
        f16x8 va = *(const f16x8*)&Vs[h][(row * 8 + (q8 ^ cc7)) * 8];        // granule kk=0
        f16x8 vb = *(const f16x8*)&Vs[h][(row * 8 + ((4 + q8) ^ cc7)) * 8];  // granule kk=1
#pragma unroll
        for (int g = 0; g < 2; ++g) {
          o[g][i] = __builtin_amdgcn_mfma_f32_16x16x32_f16(va, pf8[g][h][0], o[g][i], 0, 0, 0);
          o[g][i] = __builtin_amdgcn_mfma_f32_16x16x32_f16(vb, pf8[g][h][1], o[g][i], 0, 0, 0);
        }
      }
    }
  }
  // epilogue: reduce the deferred l partials across q8 lanes, then write O^T
  float lt0 = l_st[0], lt1 = l_st[1];
  {
    float s0 = __shfl_xor(lt0, 16);
    float s1 = __shfl_xor(lt1, 16);
    lt0 += s0; lt1 += s1;
    s0 = __shfl_xor(lt0, 32);
    s1 = __shfl_xor(lt1, 32);
    lt0 += s0; lt1 += s1;
  }
  const int bidx = bh >> 3, h = bh & 7;
#pragma unroll
  for (int g = 0; g < 2; ++g) {
    int qlg = qt * 128 + g * 64 + w * 16 + c;
    float inv = 1.0f / (g == 0 ? lt0 : lt1);
    size_t base = (size_t)(bidx * 1024 + qlg) * 512 + h * 64;
#pragma unroll
    for (int i = 0; i < 4; ++i) {
      ushort4 ov4;
      ov4.x = f2b(o[g][i][0] * inv);
      ov4.y = f2b(o[g][i][1] * inv);
      ov4.z = f2b(o[g][i][2] * inv);
      ov4.w = f2b(o[g][i][3] * inv);
      *(ushort4*)(attn_out + base + i * 16 + q8 * 4) = ov4;
    }
  }
}

extern "C" void kernel_launch(void* const* d_in, const int* in_sizes, int n_in,
                              void* d_out, int out_size, void* d_ws, size_t ws_size,
                              hipStream_t stream) {
  const float* x      = (const float*)d_in[0];
  const float* gamma  = (const float*)d_in[1];
  const float* beta   = (const float*)d_in[2];
  const float* w_qkv  = (const float*)d_in[3];
  const float* b_qkv  = (const float*)d_in[4];
  const float* w_pos  = (const float*)d_in[5];
  const float* w_out  = (const float*)d_in[6];
  const float* b_out  = (const float*)d_in[7];
  const float* u_bias = (const float*)d_in[8];
  const float* v_bias = (const float*)d_in[9];
  float* out = (float*)d_out;

  unsigned short* wsu = (unsigned short*)d_ws;
  unsigned short* xnb   = wsu;                    // 4M ushort
  unsigned short* peb   = wsu + 4194304;          // 512K
  unsigned short* wqkvb = wsu + 4718592;          // 768K
  unsigned short* wposb = wsu + 5505024;          // 256K
  unsigned short* woutb = wsu + 5767168;          // 256K
  unsigned short* qbf   = wsu + 6291456;          // 4M (bf16, pre-scaled)
  unsigned short* kbf   = wsu + 10485760;         // 4M (k bf16 -> K' after fold)
  unsigned short* vbf   = wsu + 14680064;         // 4M (fp16)
  unsigned short* vtb   = wsu + 18874368;         // 4M (fp16, permuted-transposed)
  unsigned short* attnb = wsu + 23068672;         // 4M (bf16)
  unsigned short* posbf = wsu + 27262976;         // 512K ushort (pos bf16)
  float* biasb = (float*)(wsu + 28311552);        // 64K floats (pre-scaled)

  prep1<<<11520, 256, 0, stream>>>(x, gamma, beta, xnb, peb,
                                   w_qkv, wqkvb, w_pos, wposb, w_out, woutb);
  // QKV GEMM (by<64, 64x24 blocks of 128x64) + pos GEMM (by in [64,72), bx<8) in one dispatch
  gemm2<<<dim3(24, 72), 256, 0, stream>>>(xnb, wqkvb, b_qkv, qbf, kbf, vbf,
                                          peb, wposb, posbf);
  prep2<<<3072, 256, 0, stream>>>(kbf, posbf, u_bias, v_bias, biasb, vbf, vtb);
  flash_mfma<<<dim3(8, 64), 256, 0, stream>>>(qbf, kbf, vtb, biasb, attnb);
  gemm_mfma<<<dim3(8, 128), 256, 0, stream>>>(attnb, woutb, b_out, out, 512);
}